// Round 13
// baseline (3493.179 us; speedup 1.0000x reference)
//
#include <hip/hip_runtime.h>
#include <math.h>

#define KSTEPS  256
#define DMODEL  1024
#define NLAYER  4
#define NTHREADS 512
#define JPB     16
#define SEQ0_FLOATS (KSTEPS*DMODEL)            // 1 MB
#define INITFLAG_INTS (256*32)                 // 32 KB
#define REC_OFF_FLOATS (SEQ0_FLOATS + INITFLAG_INTS)
#define REC_ULL ((size_t)NLAYER*KSTEPS*DMODEL) // 8 MB of 8B packets
#define WS_NEED_BYTES ((size_t)REC_OFF_FLOATS*4 + REC_ULL*8)
#define TIME_CAP 5000000LL                     // ~50ms backstop

typedef float f32x4 __attribute__((ext_vector_type(4)));
typedef unsigned long long u64;

__device__ __forceinline__ u64 ld_pkt(const u64* p) {
  return __hip_atomic_load(p, __ATOMIC_RELAXED, __HIP_MEMORY_SCOPE_AGENT);
}
__device__ __forceinline__ void st_pkt(u64* p, u64 v) {
  __hip_atomic_store(p, v, __ATOMIC_RELAXED, __HIP_MEMORY_SCOPE_AGENT);
}
__device__ __forceinline__ void st_agent(float* p, float v) {
  __hip_atomic_store(p, v, __ATOMIC_RELAXED, __HIP_MEMORY_SCOPE_AGENT);
}

// wave64 sum via DPP (VALU pipe only); result valid in lane 63
#define DPP_STEP(v, ctrl) \
  v += __builtin_bit_cast(float, __builtin_amdgcn_update_dpp( \
        0, __builtin_bit_cast(int, v), ctrl, 0xf, 0xf, true))
__device__ __forceinline__ float wave_sum64(float v) {
  DPP_STEP(v, 0x111);  // row_shr:1
  DPP_STEP(v, 0x112);  // row_shr:2
  DPP_STEP(v, 0x114);  // row_shr:4
  DPP_STEP(v, 0x118);  // row_shr:8
  DPP_STEP(v, 0x142);  // row_bcast:15
  DPP_STEP(v, 0x143);  // row_bcast:31
  return v;
}

__device__ __forceinline__ float tanh_fast(float s) {
  float e = __expf(2.f * s);
  return 1.f - 2.f / (e + 1.f);   // inf-safe
}

// zero rec (blocks 0..1023); initflags (block 1024)
__global__ void cfc_init(int* initflags, u64* rec) {
  if (blockIdx.x < 1024) {
    rec[(size_t)blockIdx.x * 1024 + threadIdx.x] = 0ULL;
  } else {
    int j = threadIdx.x;
    #pragma unroll
    for (int q = 0; q < 8; ++q) initflags[j * 8 + q] = 0;
  }
}

__global__ __launch_bounds__(NTHREADS, 1)
void cfc_main(const float* __restrict__ sensor_vals,   // [256][3]
              const float* __restrict__ sensor_pos,    // [256][2]
              const float* __restrict__ Bm,            // [2][256]
              const float* __restrict__ proj_w,        // [515][1024]
              const float* __restrict__ proj_b,        // [1024]
              const float* __restrict__ ff1_w, const float* __restrict__ ff1_b,
              const float* __restrict__ ff2_w, const float* __restrict__ ff2_b,
              const float* __restrict__ ta_w,  const float* __restrict__ ta_b,
              const float* __restrict__ tb_w,  const float* __restrict__ tb_b,
              float* __restrict__ out,                 // [1024]
              float* __restrict__ ws)
{
  __shared__ float smem[16384];   // 64KB: phase-0/1 only; scan loop uses none

  const long long tstart = __builtin_amdgcn_s_memrealtime();
  const int tid   = threadIdx.x;
  const int bid   = blockIdx.x;
  const int layer = bid >> 6;           // 0..3   (r8 mapping, proven)
  const int slot  = bid & 63;           // 0..63
  const int w     = tid >> 6;           // wave -> cols j0+2w, j0+2w+1
  const int lane  = tid & 63;           // lane l -> rows {256q + 4l + i}
  const int j0    = slot * JPB;

  float*    seq0      = ws;                               // [256][1024]
  int*      initflags = (int*)(ws + SEQ0_FLOATS);         // [256] stride 32
  u64*      rec       = (u64*)(ws + REC_OFF_FLOATS);      // [4][256][1024]

  // ---------------- phase 0: seq0 = RFF-proj (each block: 4 cols, all t) -----
  {
    int t  = tid & 255;
    int jp = tid >> 8;
    int jj = bid * 4 + jp * 2;
    float p0 = sensor_pos[t*2+0], p1 = sensor_pos[t*2+1];
    float a0 = 0.f, a1 = 0.f;
    for (int r = 0; r < 256; ++r) {
      float pr = p0 * Bm[r] + p1 * Bm[256 + r];
      float sn, cs;
      __sincosf(pr, &sn, &cs);
      a0 += cs * proj_w[r*1024 + jj]     + sn * proj_w[(256+r)*1024 + jj];
      a1 += cs * proj_w[r*1024 + jj + 1] + sn * proj_w[(256+r)*1024 + jj + 1];
    }
    for (int i = 0; i < 3; ++i) {
      float v = sensor_vals[t*3 + i];
      a0 += v * proj_w[(512+i)*1024 + jj];
      a1 += v * proj_w[(512+i)*1024 + jj + 1];
    }
    a0 += proj_b[jj]; a1 += proj_b[jj + 1];
    st_agent(&seq0[t*DMODEL + jj],     a0);
    st_agent(&seq0[t*DMODEL + jj + 1], a1);
    __syncthreads();
    if (tid == 0)
      __hip_atomic_store(&initflags[bid*32], 1, __ATOMIC_RELEASE, __HIP_MEMORY_SCOPE_AGENT);
  }

  // ---------------- phase 1: weights into VGPRs ------------------------------
  // wave w owns cols {j0+2w, j0+2w+1}; lane l owns rows {256q+4l+i}, k=4q+i
  // slab: smem[c*1024 + ((row + 4c) & 1023)]; rotation cancels on read
  float wx[3][2][16], wh[3][2][16];
  {
    const float* mats[4] = { ff1_w + (size_t)layer*2048*DMODEL,
                             ff2_w + (size_t)layer*2048*DMODEL,
                             ta_w  + (size_t)layer*2048*DMODEL,
                             tb_w  + (size_t)layer*2048*DMODEL };
    #pragma unroll
    for (int ph = 0; ph < 8; ++ph) {    // p = ph>>1 (mat), hf = ph&1 (x/h half)
      const int p  = ph >> 1;
      const int hf = ph & 1;
      __syncthreads();
      const float* W = mats[p];
      for (int i = 0; i < 16; ++i) {
        int f0 = (i*512 + tid) * 2;
        int rl = f0 >> 4;
        int c  = f0 & 15;
        float2 v = *(const float2*)&W[(size_t)(hf*1024 + rl)*DMODEL + j0 + c];
        smem[ c   *1024 + ((rl + 4* c   ) & 1023)] = v.x;
        smem[(c+1)*1024 + ((rl + 4*(c+1)) & 1023)] = v.y;
      }
      __syncthreads();
      #pragma unroll
      for (int cc = 0; cc < 2; ++cc) {
        const int c = 2*w + cc;
        #pragma unroll
        for (int q = 0; q < 4; ++q) {
          int rowbase = (256*q + 4*lane + 4*c) & 1023;
          f32x4 v = *(const f32x4*)&smem[c*1024 + rowbase];
          #pragma unroll
          for (int j = 0; j < 4; ++j) {
            const int k = 4*q + j;
            float vv = v[j];
            if      (ph == 0) wx[0][cc][k] = vv;
            else if (ph == 1) wh[0][cc][k] = vv;
            else if (ph == 2) wx[1][cc][k] = vv;
            else if (ph == 3) wh[1][cc][k] = vv;
            else if (ph == 4) wx[2][cc][k] = -vv;
            else if (ph == 5) wh[2][cc][k] = -vv;
            else if (ph == 6) wx[2][cc][k] += vv;
            else              wh[2][cc][k] += vv;
          }
        }
      }
    }
  }
  float bb1[2], bb2[2], bbc[2];
  #pragma unroll
  for (int cc = 0; cc < 2; ++cc) {
    int j = j0 + 2*w + cc;
    bb1[cc] = ff1_b[layer*DMODEL + j];
    bb2[cc] = ff2_b[layer*DMODEL + j];
    bbc[cc] = tb_b[layer*DMODEL + j] - ta_b[layer*DMODEL + j];
  }

  // ---------------- wait for seq0 (layer 0 only) -----------------------------
  if (layer == 0) {
    if (tid < 64) {
      for (;;) {
        int ok = 1;
        for (int q = 0; q < 4; ++q) {
          int v = __hip_atomic_load(&initflags[(tid + q*64)*32],
                                    __ATOMIC_RELAXED, __HIP_MEMORY_SCOPE_AGENT);
          ok &= (v != 0);
        }
        if (__all(ok)) break;
        if (__builtin_amdgcn_s_memrealtime() - tstart > TIME_CAP) break;
      }
      __threadfence();
    }
  }
  __syncthreads();

  // ---------------- phase 2: barrier-free scan, direct per-thread poll -------
  u64* recO = rec + (size_t)layer * KSTEPS * DMODEL;
  u64* recP = rec + (size_t)(layer > 0 ? layer-1 : 0) * KSTEPS * DMODEL;

  for (int t = 0; t < KSTEPS; ++t) {
    float a[3][2] = {};

    // ---- x: gather own 16 cols {256q+4l+i}, FMA immediately ----------------
    if (layer == 0) {
      const float* src = seq0 + (size_t)t*DMODEL + 4*lane;
      #pragma unroll
      for (int q = 0; q < 4; ++q) {
        f32x4 vx = *(const f32x4*)(src + 256*q);
        #pragma unroll
        for (int i = 0; i < 4; ++i) {
          const int k = 4*q + i;
          const float xj = vx[i];
          #pragma unroll
          for (int m = 0; m < 3; ++m)
            #pragma unroll
            for (int cc = 0; cc < 2; ++cc)
              a[m][cc] = fmaf(xj, wx[m][cc][k], a[m][cc]);
        }
      }
    } else {
      const u64* pX = recP + (size_t)t*DMODEL + 4*lane;
      const unsigned sx = (unsigned)(t + 1);
      unsigned pend = 0xFu;
      int c3 = 0;
      for (;;) {
        u64 pk[4][4];
        #pragma unroll
        for (int q = 0; q < 4; ++q)
          if (pend & (1u << q)) {
            #pragma unroll
            for (int i = 0; i < 4; ++i) pk[q][i] = ld_pkt(pX + 256*q + i);
          }
        #pragma unroll
        for (int q = 0; q < 4; ++q)
          if (pend & (1u << q)) {
            int ok = 1;
            #pragma unroll
            for (int i = 0; i < 4; ++i)
              ok &= ((unsigned)(pk[q][i] >> 32) == sx);
            if (ok) {
              #pragma unroll
              for (int i = 0; i < 4; ++i) {
                const int k = 4*q + i;
                const float xj = __int_as_float((int)(unsigned)pk[q][i]);
                #pragma unroll
                for (int m = 0; m < 3; ++m)
                  #pragma unroll
                  for (int cc = 0; cc < 2; ++cc)
                    a[m][cc] = fmaf(xj, wx[m][cc][k], a[m][cc]);
              }
              pend &= ~(1u << q);
            }
          }
        if (__all(pend == 0)) break;
        __builtin_amdgcn_s_sleep(1);
        if (((++c3) & 7) == 0 &&
            __builtin_amdgcn_s_memrealtime() - tstart > TIME_CAP) break;
      }
    }

    // ---- h: sticky spin on own 16 packets, FMA folded per resolved quad ----
    if (t > 0) {
      const u64* pH = recO + (size_t)(t-1)*DMODEL + 4*lane;
      const unsigned sh = (unsigned)t;
      unsigned pend = 0xFu;
      int c4 = 0;
      for (;;) {
        u64 pk[4][4];
        #pragma unroll
        for (int q = 0; q < 4; ++q)
          if (pend & (1u << q)) {
            #pragma unroll
            for (int i = 0; i < 4; ++i) pk[q][i] = ld_pkt(pH + 256*q + i);
          }
        #pragma unroll
        for (int q = 0; q < 4; ++q)
          if (pend & (1u << q)) {
            int ok = 1;
            #pragma unroll
            for (int i = 0; i < 4; ++i)
              ok &= ((unsigned)(pk[q][i] >> 32) == sh);
            if (ok) {
              #pragma unroll
              for (int i = 0; i < 4; ++i) {
                const int k = 4*q + i;
                const float hj = __int_as_float((int)(unsigned)pk[q][i]);
                #pragma unroll
                for (int m = 0; m < 3; ++m)
                  #pragma unroll
                  for (int cc = 0; cc < 2; ++cc)
                    a[m][cc] = fmaf(hj, wh[m][cc][k], a[m][cc]);
              }
              pend &= ~(1u << q);
            }
          }
        if (__all(pend == 0)) break;
        __builtin_amdgcn_s_sleep(1);
        if (((++c4) & 7) == 0 &&
            __builtin_amdgcn_s_memrealtime() - tstart > TIME_CAP) break;
      }
    }

    // ---- wave DPP reduce; lane 63 finalizes 2 cols
    float r[3][2];
    #pragma unroll
    for (int m = 0; m < 3; ++m)
      #pragma unroll
      for (int cc = 0; cc < 2; ++cc)
        r[m][cc] = wave_sum64(a[m][cc]);

    if (lane == 63) {
      #pragma unroll
      for (int cc = 0; cc < 2; ++cc) {
        float f1 = tanh_fast(r[0][cc] + bb1[cc]);
        float f2 = tanh_fast(r[1][cc] + bb2[cc]);
        float g  = 1.f / (1.f + __expf(-(r[2][cc] + bbc[cc])));
        float h  = f2 + g * (f1 - f2);
        int j = j0 + 2*w + cc;
        u64 pk = ((u64)(unsigned)(t + 1) << 32) | (unsigned)__float_as_int(h);
        st_pkt(recO + (size_t)t*DMODEL + j, pk);
        if (layer == NLAYER-1 && t == KSTEPS-1) out[j] = h;
      }
    }
    // no barriers in the scan loop at all
  }
}

extern "C" void kernel_launch(void* const* d_in, const int* in_sizes, int n_in,
                              void* d_out, int out_size, void* d_ws, size_t ws_size,
                              hipStream_t stream) {
  if (ws_size < WS_NEED_BYTES) return;  // informative fail, no fault

  const float* sensor_vals = (const float*)d_in[0];
  const float* sensor_pos  = (const float*)d_in[1];
  const float* Bm          = (const float*)d_in[2];
  const float* proj_w      = (const float*)d_in[3];
  const float* proj_b      = (const float*)d_in[4];
  const float* ff1_w       = (const float*)d_in[5];
  const float* ff1_b       = (const float*)d_in[6];
  const float* ff2_w       = (const float*)d_in[7];
  const float* ff2_b       = (const float*)d_in[8];
  const float* ta_w        = (const float*)d_in[9];
  const float* ta_b        = (const float*)d_in[10];
  const float* tb_w        = (const float*)d_in[11];
  const float* tb_b        = (const float*)d_in[12];
  float* ws        = (float*)d_ws;
  int* initflags   = (int*)(ws + SEQ0_FLOATS);
  u64* rec         = (u64*)(ws + REC_OFF_FLOATS);

  cfc_init<<<1025, 1024, 0, stream>>>(initflags, rec);
  cfc_main<<<256, NTHREADS, 0, stream>>>(sensor_vals, sensor_pos, Bm,
                                         proj_w, proj_b,
                                         ff1_w, ff1_b, ff2_w, ff2_b,
                                         ta_w, ta_b, tb_w, tb_b,
                                         (float*)d_out, ws);
}

// Round 14
// 1217.720 us; speedup vs baseline: 2.8686x; 2.8686x over previous
//
#include <hip/hip_runtime.h>
#include <math.h>

#define KSTEPS  256
#define DMODEL  1024
#define NLAYER  4
#define NTHREADS 512
#define JPB     16
#define SEQ0_FLOATS (KSTEPS*DMODEL)            // 1 MB
#define INITFLAG_INTS (256*32)                 // 32 KB
#define REC_OFF_FLOATS (SEQ0_FLOATS + INITFLAG_INTS)
#define REC_ULL ((size_t)NLAYER*KSTEPS*DMODEL) // 8 MB of 8B packets
#define WS_NEED_BYTES ((size_t)REC_OFF_FLOATS*4 + REC_ULL*8)
#define TIME_CAP 5000000LL                     // ~50ms backstop

typedef float f32x4 __attribute__((ext_vector_type(4)));
typedef unsigned long long u64;

__device__ __forceinline__ u64 ld_pkt(const u64* p) {
  return __hip_atomic_load(p, __ATOMIC_RELAXED, __HIP_MEMORY_SCOPE_AGENT);
}
__device__ __forceinline__ void st_pkt(u64* p, u64 v) {
  __hip_atomic_store(p, v, __ATOMIC_RELAXED, __HIP_MEMORY_SCOPE_AGENT);
}
__device__ __forceinline__ void st_agent(float* p, float v) {
  __hip_atomic_store(p, v, __ATOMIC_RELAXED, __HIP_MEMORY_SCOPE_AGENT);
}

// wave64 sum via DPP (VALU pipe only); result valid in lane 63
#define DPP_STEP(v, ctrl) \
  v += __builtin_bit_cast(float, __builtin_amdgcn_update_dpp( \
        0, __builtin_bit_cast(int, v), ctrl, 0xf, 0xf, true))
__device__ __forceinline__ float wave_sum64(float v) {
  DPP_STEP(v, 0x111);  // row_shr:1
  DPP_STEP(v, 0x112);  // row_shr:2
  DPP_STEP(v, 0x114);  // row_shr:4
  DPP_STEP(v, 0x118);  // row_shr:8
  DPP_STEP(v, 0x142);  // row_bcast:15
  DPP_STEP(v, 0x143);  // row_bcast:31
  return v;
}

__device__ __forceinline__ float tanh_fast(float s) {
  float e = __expf(2.f * s);
  return 1.f - 2.f / (e + 1.f);   // inf-safe
}

// zero rec (blocks 0..1023); initflags (block 1024)
__global__ void cfc_init(int* initflags, u64* rec) {
  if (blockIdx.x < 1024) {
    rec[(size_t)blockIdx.x * 1024 + threadIdx.x] = 0ULL;
  } else {
    int j = threadIdx.x;
    #pragma unroll
    for (int q = 0; q < 8; ++q) initflags[j * 8 + q] = 0;
  }
}

__global__ __launch_bounds__(NTHREADS, 1)
void cfc_main(const float* __restrict__ sensor_vals,   // [256][3]
              const float* __restrict__ sensor_pos,    // [256][2]
              const float* __restrict__ Bm,            // [2][256]
              const float* __restrict__ proj_w,        // [515][1024]
              const float* __restrict__ proj_b,        // [1024]
              const float* __restrict__ ff1_w, const float* __restrict__ ff1_b,
              const float* __restrict__ ff2_w, const float* __restrict__ ff2_b,
              const float* __restrict__ ta_w,  const float* __restrict__ ta_b,
              const float* __restrict__ tb_w,  const float* __restrict__ tb_b,
              float* __restrict__ out,                 // [1024]
              float* __restrict__ ws)
{
  __shared__ float smem[16384];   // 64KB: phase-1 slabs; scan uses [0,4096)

  const long long tstart = __builtin_amdgcn_s_memrealtime();
  const int tid   = threadIdx.x;
  const int bid   = blockIdx.x;
  const int layer = bid >> 6;           // 0..3   (r8 mapping, proven)
  const int slot  = bid & 63;           // 0..63
  const int w     = tid >> 6;           // wave -> cols j0+2w, j0+2w+1
  const int lane  = tid & 63;           // lane l -> rows {256q + 4l + j}
  const int j0    = slot * JPB;

  float*    seq0      = ws;                               // [256][1024]
  int*      initflags = (int*)(ws + SEQ0_FLOATS);         // [256] stride 32
  u64*      rec       = (u64*)(ws + REC_OFF_FLOATS);      // [4][256][1024]

  // ---------------- phase 0: seq0 = RFF-proj (each block: 4 cols, all t) -----
  {
    int t  = tid & 255;
    int jp = tid >> 8;
    int jj = bid * 4 + jp * 2;
    float p0 = sensor_pos[t*2+0], p1 = sensor_pos[t*2+1];
    float a0 = 0.f, a1 = 0.f;
    for (int r = 0; r < 256; ++r) {
      float pr = p0 * Bm[r] + p1 * Bm[256 + r];
      float sn, cs;
      __sincosf(pr, &sn, &cs);
      a0 += cs * proj_w[r*1024 + jj]     + sn * proj_w[(256+r)*1024 + jj];
      a1 += cs * proj_w[r*1024 + jj + 1] + sn * proj_w[(256+r)*1024 + jj + 1];
    }
    for (int i = 0; i < 3; ++i) {
      float v = sensor_vals[t*3 + i];
      a0 += v * proj_w[(512+i)*1024 + jj];
      a1 += v * proj_w[(512+i)*1024 + jj + 1];
    }
    a0 += proj_b[jj]; a1 += proj_b[jj + 1];
    st_agent(&seq0[t*DMODEL + jj],     a0);
    st_agent(&seq0[t*DMODEL + jj + 1], a1);
    __syncthreads();
    if (tid == 0)
      __hip_atomic_store(&initflags[bid*32], 1, __ATOMIC_RELEASE, __HIP_MEMORY_SCOPE_AGENT);
  }

  // ---------------- phase 1: weights into VGPRs ------------------------------
  // wave w owns cols {j0+2w, j0+2w+1}; lane l owns rows {256q+4l+j}, k=4q+j
  // slab: smem[c*1024 + ((row + 4c) & 1023)] -> writes 2-way (free),
  // reads 4x b128 per col, 64 lanes contiguous (conflict-free, 16B aligned)
  float wx[3][2][16], wh[3][2][16];
  {
    const float* mats[4] = { ff1_w + (size_t)layer*2048*DMODEL,
                             ff2_w + (size_t)layer*2048*DMODEL,
                             ta_w  + (size_t)layer*2048*DMODEL,
                             tb_w  + (size_t)layer*2048*DMODEL };
    #pragma unroll
    for (int ph = 0; ph < 8; ++ph) {    // p = ph>>1 (mat), hf = ph&1 (x/h half)
      const int p  = ph >> 1;
      const int hf = ph & 1;
      __syncthreads();
      const float* W = mats[p];
      for (int i = 0; i < 16; ++i) {
        int f0 = (i*512 + tid) * 2;
        int rl = f0 >> 4;
        int c  = f0 & 15;
        float2 v = *(const float2*)&W[(size_t)(hf*1024 + rl)*DMODEL + j0 + c];
        smem[ c   *1024 + ((rl + 4* c   ) & 1023)] = v.x;
        smem[(c+1)*1024 + ((rl + 4*(c+1)) & 1023)] = v.y;
      }
      __syncthreads();
      #pragma unroll
      for (int cc = 0; cc < 2; ++cc) {
        const int c = 2*w + cc;
        #pragma unroll
        for (int q = 0; q < 4; ++q) {
          int rowbase = (256*q + 4*lane + 4*c) & 1023;
          f32x4 v = *(const f32x4*)&smem[c*1024 + rowbase];
          #pragma unroll
          for (int j = 0; j < 4; ++j) {
            const int k = 4*q + j;
            float vv = v[j];
            if      (ph == 0) wx[0][cc][k] = vv;
            else if (ph == 1) wh[0][cc][k] = vv;
            else if (ph == 2) wx[1][cc][k] = vv;
            else if (ph == 3) wh[1][cc][k] = vv;
            else if (ph == 4) wx[2][cc][k] = -vv;
            else if (ph == 5) wh[2][cc][k] = -vv;
            else if (ph == 6) wx[2][cc][k] += vv;
            else              wh[2][cc][k] += vv;
          }
        }
      }
    }
  }
  float bb1[2], bb2[2], bbc[2];
  #pragma unroll
  for (int cc = 0; cc < 2; ++cc) {
    int j = j0 + 2*w + cc;
    bb1[cc] = ff1_b[layer*DMODEL + j];
    bb2[cc] = ff2_b[layer*DMODEL + j];
    bbc[cc] = tb_b[layer*DMODEL + j] - ta_b[layer*DMODEL + j];
  }

  // ---------------- wait for seq0 (layer 0 only) -----------------------------
  if (layer == 0) {
    if (tid < 64) {
      for (;;) {
        int ok = 1;
        for (int q = 0; q < 4; ++q) {
          int v = __hip_atomic_load(&initflags[(tid + q*64)*32],
                                    __ATOMIC_RELAXED, __HIP_MEMORY_SCOPE_AGENT);
          ok &= (v != 0);
        }
        if (__all(ok)) break;
        if (__builtin_amdgcn_s_memrealtime() - tstart > TIME_CAP) break;
      }
      __threadfence();
    }
  }
  __syncthreads();

  // ---------------- phase 2: wavefront scan ----------------------------------
  // sole sync mechanism: self-validating stamped packets, sticky per-packet spin
  // poll cadence: 2 quick sweeps (~50ns) then backoff (~270ns) — the ONLY
  // change vs r8, discriminating congestion vs intrinsic-latency theories
  u64* recO = rec + (size_t)layer * KSTEPS * DMODEL;
  u64* recP = rec + (size_t)(layer > 0 ? layer-1 : 0) * KSTEPS * DMODEL;

  for (int t = 0; t < KSTEPS; ++t) {
    const int needH = (t > 0);
    const int needX = (layer > 0);

    // ---- data gather: immediate first check, then backoff sticky spin
    const int i0 = tid << 1;
    float hva = 0.f, hvb = 0.f, xva = 0.f, xvb = 0.f;
    if (layer == 0) {
      float2 x2 = *(const float2*)&seq0[(size_t)t*DMODEL + i0];
      xva = x2.x; xvb = x2.y;
    }
    if (needH | needX) {
      const u64* pH = recO + (needH ? (size_t)(t-1)*DMODEL : 0) + i0;
      const u64* pX = recP + (size_t)t*DMODEL + i0;
      const unsigned sh = (unsigned)t, sx = (unsigned)(t + 1);
      int hok = !needH, xok = !needX;
      u64 h0 = 0, h1 = 0, x0 = 0, x1 = 0;
      int c3 = 0;
      for (;;) {
        if (!hok) { h0 = ld_pkt(pH); h1 = ld_pkt(pH + 1);
                    hok = ((unsigned)(h0 >> 32) == sh) &
                          ((unsigned)(h1 >> 32) == sh); }
        if (!xok) { x0 = ld_pkt(pX); x1 = ld_pkt(pX + 1);
                    xok = ((unsigned)(x0 >> 32) == sx) &
                          ((unsigned)(x1 >> 32) == sx); }
        if (__all(hok & xok)) break;
        ++c3;
        if (c3 < 3) __builtin_amdgcn_s_sleep(2);    // quick catch window
        else        __builtin_amdgcn_s_sleep(10);   // backoff ~270ns
        if ((c3 & 15) == 0 &&
            __builtin_amdgcn_s_memrealtime() - tstart > TIME_CAP) break;
      }
      if (needH) { hva = __int_as_float((int)(unsigned)h0);
                   hvb = __int_as_float((int)(unsigned)h1); }
      if (needX) { xva = __int_as_float((int)(unsigned)x0);
                   xvb = __int_as_float((int)(unsigned)x1); }
    }

    // ---- stage to LDS (linear, parity double-buffered; float2 writes)
    float* hbuf = smem + (t & 1) * 2048;
    float* xbuf = hbuf + 1024;
    *(float2*)&hbuf[i0] = make_float2(hva, hvb);
    *(float2*)&xbuf[i0] = make_float2(xva, xvb);
    __syncthreads();   // the single barrier per round

    // ---- FMA: 8x ds_read_b128 (contiguous per instr), 192 fma
    float a[3][2] = {};
    #pragma unroll
    for (int q = 0; q < 4; ++q) {
      f32x4 vh = *(const f32x4*)&hbuf[256*q + 4*lane];
      f32x4 vx = *(const f32x4*)&xbuf[256*q + 4*lane];
      #pragma unroll
      for (int j = 0; j < 4; ++j) {
        const int k = 4*q + j;
        const float xj = vx[j], hj = vh[j];
        #pragma unroll
        for (int m = 0; m < 3; ++m)
          #pragma unroll
          for (int cc = 0; cc < 2; ++cc)
            a[m][cc] = fmaf(xj, wx[m][cc][k], fmaf(hj, wh[m][cc][k], a[m][cc]));
      }
    }

    // ---- wave DPP reduce; lane 63 finalizes 2 cols
    float r[3][2];
    #pragma unroll
    for (int m = 0; m < 3; ++m)
      #pragma unroll
      for (int cc = 0; cc < 2; ++cc)
        r[m][cc] = wave_sum64(a[m][cc]);

    if (lane == 63) {
      #pragma unroll
      for (int cc = 0; cc < 2; ++cc) {
        float f1 = tanh_fast(r[0][cc] + bb1[cc]);
        float f2 = tanh_fast(r[1][cc] + bb2[cc]);
        float g  = 1.f / (1.f + __expf(-(r[2][cc] + bbc[cc])));
        float h  = f2 + g * (f1 - f2);
        int j = j0 + 2*w + cc;
        u64 pk = ((u64)(unsigned)(t + 1) << 32) | (unsigned)__float_as_int(h);
        st_pkt(recO + (size_t)t*DMODEL + j, pk);
        if (layer == NLAYER-1 && t == KSTEPS-1) out[j] = h;
      }
    }
    // no trailing barrier: next round writes the other LDS parity
  }
}

extern "C" void kernel_launch(void* const* d_in, const int* in_sizes, int n_in,
                              void* d_out, int out_size, void* d_ws, size_t ws_size,
                              hipStream_t stream) {
  if (ws_size < WS_NEED_BYTES) return;  // informative fail, no fault

  const float* sensor_vals = (const float*)d_in[0];
  const float* sensor_pos  = (const float*)d_in[1];
  const float* Bm          = (const float*)d_in[2];
  const float* proj_w      = (const float*)d_in[3];
  const float* proj_b      = (const float*)d_in[4];
  const float* ff1_w       = (const float*)d_in[5];
  const float* ff1_b       = (const float*)d_in[6];
  const float* ff2_w       = (const float*)d_in[7];
  const float* ff2_b       = (const float*)d_in[8];
  const float* ta_w        = (const float*)d_in[9];
  const float* ta_b        = (const float*)d_in[10];
  const float* tb_w        = (const float*)d_in[11];
  const float* tb_b        = (const float*)d_in[12];
  float* ws        = (float*)d_ws;
  int* initflags   = (int*)(ws + SEQ0_FLOATS);
  u64* rec         = (u64*)(ws + REC_OFF_FLOATS);

  cfc_init<<<1025, 1024, 0, stream>>>(initflags, rec);
  cfc_main<<<256, NTHREADS, 0, stream>>>(sensor_vals, sensor_pos, Bm,
                                         proj_w, proj_b,
                                         ff1_w, ff1_b, ff2_w, ff2_b,
                                         ta_w, ta_b, tb_w, tb_b,
                                         (float*)d_out, ws);
}

// Round 15
// 1104.908 us; speedup vs baseline: 3.1615x; 1.1021x over previous
//
#include <hip/hip_runtime.h>
#include <math.h>

#define KSTEPS  256
#define DMODEL  1024
#define NLAYER  4
#define NTHREADS 512
#define JPB     16
#define SEQ0_FLOATS (KSTEPS*DMODEL)            // 1 MB
#define INITFLAG_INTS (256*32)                 // 32 KB
#define REC_OFF_FLOATS (SEQ0_FLOATS + INITFLAG_INTS)
#define REC_ULL ((size_t)NLAYER*KSTEPS*DMODEL) // 8 MB of 8B packets
#define WS_NEED_BYTES ((size_t)REC_OFF_FLOATS*4 + REC_ULL*8)
#define TIME_CAP 5000000LL                     // ~50ms backstop

typedef float f32x4 __attribute__((ext_vector_type(4)));
typedef unsigned long long u64;

__device__ __forceinline__ u64 ld_pkt(const u64* p) {
  return __hip_atomic_load(p, __ATOMIC_RELAXED, __HIP_MEMORY_SCOPE_AGENT);
}
__device__ __forceinline__ void st_pkt(u64* p, u64 v) {
  __hip_atomic_store(p, v, __ATOMIC_RELAXED, __HIP_MEMORY_SCOPE_AGENT);
}
__device__ __forceinline__ void st_agent(float* p, float v) {
  __hip_atomic_store(p, v, __ATOMIC_RELAXED, __HIP_MEMORY_SCOPE_AGENT);
}

// wave64 sum via DPP (VALU pipe only); result valid in lane 63
#define DPP_STEP(v, ctrl) \
  v += __builtin_bit_cast(float, __builtin_amdgcn_update_dpp( \
        0, __builtin_bit_cast(int, v), ctrl, 0xf, 0xf, true))
__device__ __forceinline__ float wave_sum64(float v) {
  DPP_STEP(v, 0x111);  // row_shr:1
  DPP_STEP(v, 0x112);  // row_shr:2
  DPP_STEP(v, 0x114);  // row_shr:4
  DPP_STEP(v, 0x118);  // row_shr:8
  DPP_STEP(v, 0x142);  // row_bcast:15
  DPP_STEP(v, 0x143);  // row_bcast:31
  return v;
}

__device__ __forceinline__ float tanh_fast(float s) {
  float e = __expf(2.f * s);
  return 1.f - 2.f / (e + 1.f);   // inf-safe
}

// zero rec (blocks 0..1023); initflags (block 1024)
__global__ void cfc_init(int* initflags, u64* rec) {
  if (blockIdx.x < 1024) {
    rec[(size_t)blockIdx.x * 1024 + threadIdx.x] = 0ULL;
  } else {
    int j = threadIdx.x;
    #pragma unroll
    for (int q = 0; q < 8; ++q) initflags[j * 8 + q] = 0;
  }
}

__global__ __launch_bounds__(NTHREADS, 1)
void cfc_main(const float* __restrict__ sensor_vals,   // [256][3]
              const float* __restrict__ sensor_pos,    // [256][2]
              const float* __restrict__ Bm,            // [2][256]
              const float* __restrict__ proj_w,        // [515][1024]
              const float* __restrict__ proj_b,        // [1024]
              const float* __restrict__ ff1_w, const float* __restrict__ ff1_b,
              const float* __restrict__ ff2_w, const float* __restrict__ ff2_b,
              const float* __restrict__ ta_w,  const float* __restrict__ ta_b,
              const float* __restrict__ tb_w,  const float* __restrict__ tb_b,
              float* __restrict__ out,                 // [1024]
              float* __restrict__ ws)
{
  __shared__ float smem[16384];   // 64KB: phase-1 slabs; scan uses [0,4096)

  const long long tstart = __builtin_amdgcn_s_memrealtime();
  const int tid   = threadIdx.x;
  const int bid   = blockIdx.x;
  const int layer = bid & 3;            // XCD-affinity: layer l -> XCDs {l, l+4}
  const int slot  = bid >> 2;           // 0..63
  const int w     = tid >> 6;           // wave -> cols j0+2w, j0+2w+1
  const int lane  = tid & 63;           // lane l -> rows {256q + 4l + j}
  const int j0    = slot * JPB;

  float*    seq0      = ws;                               // [256][1024]
  int*      initflags = (int*)(ws + SEQ0_FLOATS);         // [256] stride 32
  u64*      rec       = (u64*)(ws + REC_OFF_FLOATS);      // [4][256][1024]

  // ---------------- phase 0: seq0 = RFF-proj (each block: 4 cols, all t) -----
  {
    int t  = tid & 255;
    int jp = tid >> 8;
    int jj = bid * 4 + jp * 2;          // bid-based: covers all 1024 cols
    float p0 = sensor_pos[t*2+0], p1 = sensor_pos[t*2+1];
    float a0 = 0.f, a1 = 0.f;
    for (int r = 0; r < 256; ++r) {
      float pr = p0 * Bm[r] + p1 * Bm[256 + r];
      float sn, cs;
      __sincosf(pr, &sn, &cs);
      a0 += cs * proj_w[r*1024 + jj]     + sn * proj_w[(256+r)*1024 + jj];
      a1 += cs * proj_w[r*1024 + jj + 1] + sn * proj_w[(256+r)*1024 + jj + 1];
    }
    for (int i = 0; i < 3; ++i) {
      float v = sensor_vals[t*3 + i];
      a0 += v * proj_w[(512+i)*1024 + jj];
      a1 += v * proj_w[(512+i)*1024 + jj + 1];
    }
    a0 += proj_b[jj]; a1 += proj_b[jj + 1];
    st_agent(&seq0[t*DMODEL + jj],     a0);
    st_agent(&seq0[t*DMODEL + jj + 1], a1);
    __syncthreads();
    if (tid == 0)
      __hip_atomic_store(&initflags[bid*32], 1, __ATOMIC_RELEASE, __HIP_MEMORY_SCOPE_AGENT);
  }

  // ---------------- phase 1: weights into VGPRs ------------------------------
  // wave w owns cols {j0+2w, j0+2w+1}; lane l owns rows {256q+4l+j}, k=4q+j
  // slab: smem[c*1024 + ((row + 4c) & 1023)] -> writes 2-way (free),
  // reads 4x b128 per col, 64 lanes contiguous (conflict-free, 16B aligned)
  float wx[3][2][16], wh[3][2][16];
  {
    const float* mats[4] = { ff1_w + (size_t)layer*2048*DMODEL,
                             ff2_w + (size_t)layer*2048*DMODEL,
                             ta_w  + (size_t)layer*2048*DMODEL,
                             tb_w  + (size_t)layer*2048*DMODEL };
    #pragma unroll
    for (int ph = 0; ph < 8; ++ph) {    // p = ph>>1 (mat), hf = ph&1 (x/h half)
      const int p  = ph >> 1;
      const int hf = ph & 1;
      __syncthreads();
      const float* W = mats[p];
      for (int i = 0; i < 16; ++i) {
        int f0 = (i*512 + tid) * 2;
        int rl = f0 >> 4;
        int c  = f0 & 15;
        float2 v = *(const float2*)&W[(size_t)(hf*1024 + rl)*DMODEL + j0 + c];
        smem[ c   *1024 + ((rl + 4* c   ) & 1023)] = v.x;
        smem[(c+1)*1024 + ((rl + 4*(c+1)) & 1023)] = v.y;
      }
      __syncthreads();
      #pragma unroll
      for (int cc = 0; cc < 2; ++cc) {
        const int c = 2*w + cc;
        #pragma unroll
        for (int q = 0; q < 4; ++q) {
          int rowbase = (256*q + 4*lane + 4*c) & 1023;
          f32x4 v = *(const f32x4*)&smem[c*1024 + rowbase];
          #pragma unroll
          for (int j = 0; j < 4; ++j) {
            const int k = 4*q + j;
            float vv = v[j];
            if      (ph == 0) wx[0][cc][k] = vv;
            else if (ph == 1) wh[0][cc][k] = vv;
            else if (ph == 2) wx[1][cc][k] = vv;
            else if (ph == 3) wh[1][cc][k] = vv;
            else if (ph == 4) wx[2][cc][k] = -vv;
            else if (ph == 5) wh[2][cc][k] = -vv;
            else if (ph == 6) wx[2][cc][k] += vv;
            else              wh[2][cc][k] += vv;
          }
        }
      }
    }
  }
  float bb1[2], bb2[2], bbc[2];
  #pragma unroll
  for (int cc = 0; cc < 2; ++cc) {
    int j = j0 + 2*w + cc;
    bb1[cc] = ff1_b[layer*DMODEL + j];
    bb2[cc] = ff2_b[layer*DMODEL + j];
    bbc[cc] = tb_b[layer*DMODEL + j] - ta_b[layer*DMODEL + j];
  }

  // ---------------- wait for seq0 (layer 0 only) -----------------------------
  if (layer == 0) {
    if (tid < 64) {
      for (;;) {
        int ok = 1;
        for (int q = 0; q < 4; ++q) {
          int v = __hip_atomic_load(&initflags[(tid + q*64)*32],
                                    __ATOMIC_RELAXED, __HIP_MEMORY_SCOPE_AGENT);
          ok &= (v != 0);
        }
        if (__all(ok)) break;
        if (__builtin_amdgcn_s_memrealtime() - tstart > TIME_CAP) break;
      }
      __threadfence();
    }
  }
  __syncthreads();

  // ---------------- phase 2: wavefront scan ----------------------------------
  // sole sync mechanism: self-validating stamped packets, sticky per-packet spin
  u64* recO = rec + (size_t)layer * KSTEPS * DMODEL;
  u64* recP = rec + (size_t)(layer > 0 ? layer-1 : 0) * KSTEPS * DMODEL;

  for (int t = 0; t < KSTEPS; ++t) {
    const int needH = (t > 0);
    const int needX = (layer > 0);

    // ---- data gather: immediate first check, then paced sticky spin
    const int i0 = tid << 1;
    float hva = 0.f, hvb = 0.f, xva = 0.f, xvb = 0.f;
    if (layer == 0) {
      float2 x2 = *(const float2*)&seq0[(size_t)t*DMODEL + i0];
      xva = x2.x; xvb = x2.y;
    }
    if (needH | needX) {
      const u64* pH = recO + (needH ? (size_t)(t-1)*DMODEL : 0) + i0;
      const u64* pX = recP + (size_t)t*DMODEL + i0;
      const unsigned sh = (unsigned)t, sx = (unsigned)(t + 1);
      int hok = !needH, xok = !needX;
      u64 h0 = 0, h1 = 0, x0 = 0, x1 = 0;
      int c3 = 0;
      for (;;) {
        if (!hok) { h0 = ld_pkt(pH); h1 = ld_pkt(pH + 1);
                    hok = ((unsigned)(h0 >> 32) == sh) &
                          ((unsigned)(h1 >> 32) == sh); }
        if (!xok) { x0 = ld_pkt(pX); x1 = ld_pkt(pX + 1);
                    xok = ((unsigned)(x0 >> 32) == sx) &
                          ((unsigned)(x1 >> 32) == sx); }
        if (__all(hok & xok)) break;
        __builtin_amdgcn_s_sleep(2);
        if (((++c3) & 31) == 0 &&
            __builtin_amdgcn_s_memrealtime() - tstart > TIME_CAP) break;
      }
      if (needH) { hva = __int_as_float((int)(unsigned)h0);
                   hvb = __int_as_float((int)(unsigned)h1); }
      if (needX) { xva = __int_as_float((int)(unsigned)x0);
                   xvb = __int_as_float((int)(unsigned)x1); }
    }

    // ---- stage to LDS (linear, parity double-buffered; float2 writes)
    float* hbuf = smem + (t & 1) * 2048;
    float* xbuf = hbuf + 1024;
    *(float2*)&hbuf[i0] = make_float2(hva, hvb);
    *(float2*)&xbuf[i0] = make_float2(xva, xvb);
    __syncthreads();   // the single barrier per round

    // ---- FMA: 8x ds_read_b128 (contiguous per instr), 192 fma
    float a[3][2] = {};
    #pragma unroll
    for (int q = 0; q < 4; ++q) {
      f32x4 vh = *(const f32x4*)&hbuf[256*q + 4*lane];
      f32x4 vx = *(const f32x4*)&xbuf[256*q + 4*lane];
      #pragma unroll
      for (int j = 0; j < 4; ++j) {
        const int k = 4*q + j;
        const float xj = vx[j], hj = vh[j];
        #pragma unroll
        for (int m = 0; m < 3; ++m)
          #pragma unroll
          for (int cc = 0; cc < 2; ++cc)
            a[m][cc] = fmaf(xj, wx[m][cc][k], fmaf(hj, wh[m][cc][k], a[m][cc]));
      }
    }

    // ---- wave DPP reduce; lane 63 finalizes 2 cols
    float r[3][2];
    #pragma unroll
    for (int m = 0; m < 3; ++m)
      #pragma unroll
      for (int cc = 0; cc < 2; ++cc)
        r[m][cc] = wave_sum64(a[m][cc]);

    if (lane == 63) {
      #pragma unroll
      for (int cc = 0; cc < 2; ++cc) {
        float f1 = tanh_fast(r[0][cc] + bb1[cc]);
        float f2 = tanh_fast(r[1][cc] + bb2[cc]);
        float g  = 1.f / (1.f + __expf(-(r[2][cc] + bbc[cc])));
        float h  = f2 + g * (f1 - f2);
        int j = j0 + 2*w + cc;
        u64 pk = ((u64)(unsigned)(t + 1) << 32) | (unsigned)__float_as_int(h);
        st_pkt(recO + (size_t)t*DMODEL + j, pk);
        if (layer == NLAYER-1 && t == KSTEPS-1) out[j] = h;
      }
    }
    // no trailing barrier: next round writes the other LDS parity
  }
}

extern "C" void kernel_launch(void* const* d_in, const int* in_sizes, int n_in,
                              void* d_out, int out_size, void* d_ws, size_t ws_size,
                              hipStream_t stream) {
  if (ws_size < WS_NEED_BYTES) return;  // informative fail, no fault

  const float* sensor_vals = (const float*)d_in[0];
  const float* sensor_pos  = (const float*)d_in[1];
  const float* Bm          = (const float*)d_in[2];
  const float* proj_w      = (const float*)d_in[3];
  const float* proj_b      = (const float*)d_in[4];
  const float* ff1_w       = (const float*)d_in[5];
  const float* ff1_b       = (const float*)d_in[6];
  const float* ff2_w       = (const float*)d_in[7];
  const float* ff2_b       = (const float*)d_in[8];
  const float* ta_w        = (const float*)d_in[9];
  const float* ta_b        = (const float*)d_in[10];
  const float* tb_w        = (const float*)d_in[11];
  const float* tb_b        = (const float*)d_in[12];
  float* ws        = (float*)d_ws;
  int* initflags   = (int*)(ws + SEQ0_FLOATS);
  u64* rec         = (u64*)(ws + REC_OFF_FLOATS);

  cfc_init<<<1025, 1024, 0, stream>>>(initflags, rec);
  cfc_main<<<256, NTHREADS, 0, stream>>>(sensor_vals, sensor_pos, Bm,
                                         proj_w, proj_b,
                                         ff1_w, ff1_b, ff2_w, ff2_b,
                                         ta_w, ta_b, tb_w, tb_b,
                                         (float*)d_out, ws);
}